// Round 11
// baseline (383.521 us; speedup 1.0000x reference)
//
#include <hip/hip_runtime.h>

typedef unsigned short u16;
typedef unsigned int u32;

using bf16x8 = __attribute__((ext_vector_type(8))) __bf16;
using f32x4  = __attribute__((ext_vector_type(4))) float;
using u16x4  = __attribute__((ext_vector_type(4))) unsigned short;

__device__ __forceinline__ f32x4 MFMA(bf16x8 a, bf16x8 b, f32x4 c) {
    return __builtin_amdgcn_mfma_f32_16x16x32_bf16(a, b, c, 0, 0, 0);
}

__device__ __forceinline__ u16 f2bf(float f) {
    u32 u = __builtin_bit_cast(u32, f);
    u = (u + 0x7FFFu + ((u >> 16) & 1u)) >> 16;
    return (u16)u;
}
__device__ __forceinline__ float bf2f(u16 h) {
    return __builtin_bit_cast(float, (u32)h << 16);
}

typedef const __attribute__((address_space(1))) unsigned int* gp_t;
typedef __attribute__((address_space(3))) unsigned int* lp_t;

__device__ __forceinline__ void gload16(const void* g, void* l) {
    __builtin_amdgcn_global_load_lds((gp_t)g, (lp_t)l, 16, 0, 0);
}

// ---------------- constants ----------------
#define NPADR  1156   // 34*34

// workspace layout (bytes)
static constexpr size_t OFF_XT   = 0;
static constexpr size_t OFF_YT   = OFF_XT  + (size_t)16*1024*512*2;
static constexpr size_t OFF_PJX  = OFF_YT  + (size_t)16*1024*512*2;
static constexpr size_t OFF_PJY  = OFF_PJX + (size_t)16*1024*128*2;
static constexpr size_t OFF_PV   = OFF_PJY + (size_t)16*1024*128*2;
static constexpr size_t OFF_AD   = OFF_PV  + (size_t)16*512*1024*2;
static constexpr size_t OFF_ATTN = OFF_AD  + (size_t)16*512*1024*2;
static constexpr size_t OFF_ATT2 = OFF_ATTN+ (size_t)16*1024*1024*2;
static constexpr size_t OFF_CATT = OFF_ATT2+ (size_t)16*1024*1024*2;
static constexpr size_t OFF_WQK  = OFF_CATT+ (size_t)16*1156*1024*2;
static constexpr size_t OFF_WV   = OFF_WQK + (size_t)128*512*2;
static constexpr size_t OFF_WT   = OFF_WV  + (size_t)512*512*2;
static constexpr size_t OFF_SA   = OFF_WT  + (size_t)9*512*1024*2;
static constexpr size_t OFF_OA   = OFF_SA  + (size_t)16*512*4;
static constexpr size_t OFF_TM   = OFF_OA  + (size_t)16*512*4;

// ---------------- weight prep ----------------
__global__ __launch_bounds__(256) void k_prep_w(const float* __restrict__ Wq,
                                                const float* __restrict__ Wk,
                                                const float* __restrict__ Wv,
                                                u16* __restrict__ wqk, u16* __restrict__ wv) {
    int i = blockIdx.x * 256 + threadIdx.x;
    if (i < 128 * 512) {
        float v = (i < 64 * 512) ? Wq[i] : Wk[i - 64 * 512];
        wqk[i] = f2bf(v);
    }
    if (i < 512 * 512) wv[i] = f2bf(Wv[i]);
}

__global__ __launch_bounds__(256) void k_prep_wt(const float* __restrict__ Wc, u16* __restrict__ wt) {
    int e = blockIdx.x * 256 + threadIdx.x;
    const float* src = Wc + (size_t)e * 9;
#pragma unroll
    for (int tap = 0; tap < 9; tap++) wt[(size_t)tap * 524288 + e] = f2bf(src[tap]);
}

// ---------------- zero catT borders ----------------
__global__ __launch_bounds__(256) void k_border(u16* __restrict__ catT) {
    int cell = blockIdx.x, b = blockIdx.y;
    int row, col;
    if (cell < 34)       { row = 0;  col = cell; }
    else if (cell < 68)  { row = 33; col = cell - 34; }
    else if (cell < 100) { row = cell - 68 + 1;  col = 0; }
    else                 { row = cell - 100 + 1; col = 33; }
    u16* dst = catT + ((size_t)b * NPADR + row * 34 + col) * 1024;
    u16x4 z = {0, 0, 0, 0};
    ((u16x4*)dst)[threadIdx.x] = z;
}

// ---------------- stats + fused AdaIN (ad = inp*s + o) ----------------
__global__ __launch_bounds__(256) void k_stats(const float* __restrict__ x, const float* __restrict__ inp,
                                               u16* __restrict__ ad, float* __restrict__ tmA) {
    int row = blockIdx.x;  // b*512+c
    int t = threadIdx.x;
    const float4* xr = (const float4*)(x + (size_t)row * 1024);
    const float4* ir = (const float4*)(inp + (size_t)row * 1024);
    float4 a = xr[t], c = ir[t];
    float s1 = a.x + a.y + a.z + a.w;
    float s2 = a.x * a.x + a.y * a.y + a.z * a.z + a.w * a.w;
    float p1 = c.x + c.y + c.z + c.w;
    float p2 = c.x * c.x + c.y * c.y + c.z * c.z + c.w * c.w;
#pragma unroll
    for (int m = 32; m; m >>= 1) {
        s1 += __shfl_xor(s1, m); s2 += __shfl_xor(s2, m);
        p1 += __shfl_xor(p1, m); p2 += __shfl_xor(p2, m);
    }
    __shared__ float red[4][4];
    __shared__ float bcast[2];
    int wv = t >> 6;
    if ((t & 63) == 0) { red[wv][0] = s1; red[wv][1] = s2; red[wv][2] = p1; red[wv][3] = p2; }
    __syncthreads();
    if (t == 0) {
        s1 = red[0][0] + red[1][0] + red[2][0] + red[3][0];
        s2 = red[0][1] + red[1][1] + red[2][1] + red[3][1];
        p1 = red[0][2] + red[1][2] + red[2][2] + red[3][2];
        p2 = red[0][3] + red[1][3] + red[2][3] + red[3][3];
        float tm = s1 * (1.0f / 1024.0f);
        float ts = sqrtf((s2 - 1024.0f * tm * tm) * (1.0f / 1023.0f) + 1e-5f);
        float im = p1 * (1.0f / 1024.0f);
        float is = sqrtf((p2 - 1024.0f * im * im) * (1.0f / 1023.0f) + 1e-5f);
        float sc = ts / is;
        bcast[0] = sc; bcast[1] = tm - im * sc;
        tmA[row] = tm;
    }
    __syncthreads();
    float sc = bcast[0], of = bcast[1];
    u16x4 r;
    r[0] = f2bf(c.x * sc + of); r[1] = f2bf(c.y * sc + of);
    r[2] = f2bf(c.z * sc + of); r[3] = f2bf(c.w * sc + of);
    ((u16x4*)(ad + (size_t)row * 1024))[t] = r;
}

// ---------------- transpose x,y -> bf16 [n][c] ----------------
__global__ __launch_bounds__(256) void k_transpose(const float* __restrict__ x, const float* __restrict__ y,
                                                   u16* __restrict__ xT, u16* __restrict__ yT) {
    __shared__ float tile[64][65];
    int b = blockIdx.y;
    int ct = blockIdx.x >> 4;
    int nt = blockIdx.x & 15;
    const float* src = blockIdx.z ? y : x;
    u16* dst = blockIdx.z ? yT : xT;
    int c0 = ct * 64, n0 = nt * 64;
    int ln = threadIdx.x & 63, wv = threadIdx.x >> 6;
#pragma unroll
    for (int i = 0; i < 16; i++) {
        int cl = wv + i * 4;
        tile[cl][ln] = src[((size_t)(b * 512 + c0 + cl)) * 1024 + n0 + ln];
    }
    __syncthreads();
#pragma unroll
    for (int i = 0; i < 16; i++) {
        int nl = wv + i * 4;
        dst[((size_t)(b * 1024 + n0 + nl)) * 512 + c0 + ln] = f2bf(tile[ln][nl]);
    }
}

// ---------------- staged 128x128 GEMM core (4-slot, depth-3 counted vmcnt) ----------------
template <int KTOT, int LDA, int LDB>
__device__ __forceinline__ void gemm128(const u16* __restrict__ Aorig, const u16* __restrict__ Borig,
                                        f32x4 (&acc)[4][4]) {
    __shared__ __align__(16) u16 lds[32768];  // A: 4x8KB @0 ; B: 4x8KB @32KB
    constexpr int NT = KTOT / 32;
    const int tid = threadIdx.x;
    const int l = tid & 63, w = tid >> 6;
    const int lr = l & 15, lg = l >> 4;
    const int moff = (w >> 1) * 64, coff = (w & 1) * 64;
    char* ldsb = (char*)lds;
    auto stage = [&](const u16* orig, int ldx, int bufByte) {
#pragma unroll
        for (int it = 0; it < 2; it++) {
            int slot = it * 256 + tid;
            gload16(orig + (size_t)(slot & 127) * ldx + (slot >> 7) * 8,
                    ldsb + bufByte + it * 4096 + w * 1024);
        }
    };
    auto stageT = [&](int t, int s) {
        stage(Aorig + t * 32, LDA, s * 8192);
        stage(Borig + t * 32, LDB, 32768 + s * 8192);
    };
    stageT(0, 0);
    stageT(1, 1);
    stageT(2, 2);
#pragma unroll 1
    for (int q = 0; q < NT; q++) {
        int qq = q + 3; if (qq >= NT) qq -= NT;
        stageT(qq, (q + 3) & 3);
        asm volatile("s_waitcnt vmcnt(12)" ::: "memory");
        __builtin_amdgcn_s_barrier();
        const char* A = ldsb + (q & 3) * 8192;
        const char* B = ldsb + 32768 + (q & 3) * 8192;
        bf16x8 af[4], bb[4];
#pragma unroll
        for (int i = 0; i < 4; i++) af[i] = *(const bf16x8*)(A + lg * 2048 + (moff + 16 * i + lr) * 16);
#pragma unroll
        for (int i = 0; i < 4; i++) bb[i] = *(const bf16x8*)(B + lg * 2048 + (coff + 16 * i + lr) * 16);
        __builtin_amdgcn_s_setprio(1);
#pragma unroll
        for (int ri = 0; ri < 4; ri++)
#pragma unroll
            for (int ci = 0; ci < 4; ci++) acc[ri][ci] = MFMA(af[ri], bb[ci], acc[ri][ci]);
        __builtin_amdgcn_s_setprio(0);
        __builtin_amdgcn_s_barrier();
    }
    asm volatile("s_waitcnt vmcnt(0)" ::: "memory");
}

// ---------------- projections via staged gemm128 ----------------
__global__ __launch_bounds__(256) void k_proj(const u16* __restrict__ xT, const u16* __restrict__ yT,
                                              const u16* __restrict__ wqk, const float* __restrict__ bq,
                                              const float* __restrict__ bk, u16* __restrict__ pjx,
                                              u16* __restrict__ pjy) {
    int b = blockIdx.y;
    const u16* S = blockIdx.z ? yT : xT;
    u16* D = blockIdx.z ? pjy : pjx;
    int nb = blockIdx.x * 128;
    f32x4 acc[4][4];
#pragma unroll
    for (int i = 0; i < 4; i++)
#pragma unroll
        for (int j = 0; j < 4; j++) acc[i][j] = f32x4{0.f, 0.f, 0.f, 0.f};
    gemm128<512, 512, 512>(S + ((size_t)b * 1024 + nb) * 512, wqk, acc);
    int l = threadIdx.x & 63, w = threadIdx.x >> 6;
    int lr = l & 15, lg = l >> 4;
    int moff = (w >> 1) * 64, coff = (w & 1) * 64;
#pragma unroll
    for (int ri = 0; ri < 4; ri++) {
#pragma unroll
        for (int r = 0; r < 4; r++) {
            int n = nb + moff + 16 * ri + 4 * lg + r;
#pragma unroll
            for (int ci = 0; ci < 4; ci++) {
                int cq = coff + 16 * ci + lr;
                float bias = (cq < 64) ? bq[cq] : bk[cq - 64];
                D[((size_t)b * 1024 + n) * 128 + cq] = f2bf(acc[ri][ci][r] + bias);
            }
        }
    }
}

// ---------------- pv = Wv @ x + bv ----------------
__global__ __launch_bounds__(256) void k_pv(const u16* __restrict__ xT, const u16* __restrict__ wv,
                                            const float* __restrict__ bv, u16* __restrict__ pv) {
    int b = blockIdx.z;
    int mb = blockIdx.y * 128;
    int nb = blockIdx.x * 128;
    f32x4 acc[4][4];
#pragma unroll
    for (int i = 0; i < 4; i++)
#pragma unroll
        for (int j = 0; j < 4; j++) acc[i][j] = f32x4{0.f, 0.f, 0.f, 0.f};
    gemm128<512, 512, 512>(wv + (size_t)mb * 512, xT + ((size_t)b * 1024 + nb) * 512, acc);
    int l = threadIdx.x & 63, w = threadIdx.x >> 6;
    int lr = l & 15, lg = l >> 4;
    int moff = (w >> 1) * 64, coff = (w & 1) * 64;
#pragma unroll
    for (int ri = 0; ri < 4; ri++) {
#pragma unroll
        for (int r = 0; r < 4; r++) {
            int co = mb + moff + 16 * ri + 4 * lg + r;
            float bias = bv[co];
#pragma unroll
            for (int ci = 0; ci < 4; ci++) {
                int n = nb + coff + 16 * ci + lr;
                pv[((size_t)b * 512 + co) * 1024 + n] = f2bf(acc[ri][ci][r] + bias);
            }
        }
    }
}

// ---------------- score + softmax (reference-point, single-exp) ----------------
__global__ __launch_bounds__(256) void k_score(const u16* __restrict__ pjx, const u16* __restrict__ pjy,
                                               u16* __restrict__ attnA, u16* __restrict__ attnB) {
    const u16* qT = blockIdx.y ? pjy : pjx;
    const u16* kT = blockIdx.y ? pjx : pjy;
    u16* attn = blockIdx.y ? attnB : attnA;
    int g = blockIdx.x * 4 + (threadIdx.x >> 6);
    int b = g >> 6, rb = g & 63;
    int l = threadIdx.x & 63, lr = l & 15, lg = l >> 4;
    int mb = rb * 16;
    const u16* qbase = qT + ((size_t)b * 1024 + mb + lr) * 128 + lg * 8;
    bf16x8 a0 = *(const bf16x8*)(qbase);
    bf16x8 a1 = *(const bf16x8*)(qbase + 32);
    const u16* kbase = kT + ((size_t)b * 1024 + lr) * 128 + 64 + lg * 8;
    f32x4 zero = {0.f, 0.f, 0.f, 0.f};
    float ref[4], srun[4];
    {
        bf16x8 b0 = *(const bf16x8*)(kbase);
        bf16x8 b1 = *(const bf16x8*)(kbase + 32);
        f32x4 acc = zero;
        acc = MFMA(a0, b0, acc);
        acc = MFMA(a1, b1, acc);
#pragma unroll
        for (int r = 0; r < 4; r++) { ref[r] = acc[r] * 0.125f; srun[r] = 1.0f; }
    }
    for (int cf = 1; cf < 64; cf++) {
        bf16x8 b0 = *(const bf16x8*)(kbase + (size_t)cf * 16 * 128);
        bf16x8 b1 = *(const bf16x8*)(kbase + (size_t)cf * 16 * 128 + 32);
        f32x4 acc = zero;
        acc = MFMA(a0, b0, acc);
        acc = MFMA(a1, b1, acc);
#pragma unroll
        for (int r = 0; r < 4; r++) srun[r] += __expf(acc[r] * 0.125f - ref[r]);
    }
    float inv[4];
#pragma unroll
    for (int r = 0; r < 4; r++) {
        float R = __shfl(ref[r], l & 0x30);
        srun[r] *= __expf(ref[r] - R);
#pragma unroll
        for (int m = 1; m < 16; m <<= 1) srun[r] += __shfl_xor(srun[r], m);
        ref[r] = R;
        inv[r] = 1.0f / srun[r];
    }
    for (int cf = 0; cf < 64; cf++) {
        bf16x8 b0 = *(const bf16x8*)(kbase + (size_t)cf * 16 * 128);
        bf16x8 b1 = *(const bf16x8*)(kbase + (size_t)cf * 16 * 128 + 32);
        f32x4 acc = zero;
        acc = MFMA(a0, b0, acc);
        acc = MFMA(a1, b1, acc);
#pragma unroll
        for (int r = 0; r < 4; r++) {
            float v = __expf(acc[r] * 0.125f - ref[r]) * inv[r];
            attn[((size_t)b * 1024 + mb + 4 * lg + r) * 1024 + cf * 16 + lr] = f2bf(v);
        }
    }
}

// ---------------- value GEMMs: 256x256 block tile, 8 waves of 64x128 ----------------
__global__ __launch_bounds__(512, 2) void k_value(const u16* __restrict__ attnA, const u16* __restrict__ attnB,
                                                  const u16* __restrict__ pv, const u16* __restrict__ ad,
                                                  const u16* __restrict__ xT, const float* __restrict__ tmA,
                                                  const float* __restrict__ alpha, const float* __restrict__ beta,
                                                  u16* __restrict__ catT) {
    extern __shared__ __align__(16) char dyn[];
    const int id = blockIdx.x;
    const int xcd = id & 7, j = id >> 3;
    const int z = xcd + 8 * (j & 3);
    const int tile = j >> 2;
    const int mbt = tile & 3, cbt = tile >> 2;
    const int b = z & 15, var = z >> 4;
    const u16* Aorig = (var ? attnB : attnA) + ((size_t)b * 1024 + mbt * 256) * 1024;
    const u16* Borig = (var ? ad : pv) + ((size_t)b * 512 + cbt * 256) * 1024;

    const int tid = threadIdx.x;
    const int l = tid & 63, w = tid >> 6;
    const int lr = l & 15, lg = l >> 4;
    const int ow = w >> 1, pw = w & 1;

    auto stageT = [&](int t, int s) {
        char* base = dyn + s * 32768;
#pragma unroll
        for (int it = 0; it < 2; it++) {
            int idx = it * 512 + tid;
            int row = idx & 255, g = idx >> 8;
            gload16(Aorig + (size_t)row * 1024 + t * 32 + g * 8, base + g * 4096 + row * 16);
        }
#pragma unroll
        for (int it = 0; it < 2; it++) {
            int idx = it * 512 + tid;
            int row = idx & 255, g = idx >> 8;
            gload16(Borig + (size_t)row * 1024 + t * 32 + g * 8, base + 16384 + g * 4096 + row * 16);
        }
    };

    f32x4 acc[4][8];
#pragma unroll
    for (int i = 0; i < 4; i++)
#pragma unroll
        for (int jj = 0; jj < 8; jj++) acc[i][jj] = f32x4{0.f, 0.f, 0.f, 0.f};

    stageT(0, 0);
    stageT(1, 1);
#pragma unroll 1
    for (int q = 0; q < 32; q++) {
        int qq = q + 2; if (qq >= 32) qq -= 32;
        stageT(qq, (q + 2) % 3);
        asm volatile("s_waitcnt vmcnt(8)" ::: "memory");
        __builtin_amdgcn_s_barrier();
        const char* A = dyn + (q % 3) * 32768;
        const char* B = A + 16384;
        bf16x8 af[4], bb[8];
#pragma unroll
        for (int i = 0; i < 4; i++) af[i] = *(const bf16x8*)(A + lg * 4096 + (ow * 64 + 16 * i + lr) * 16);
#pragma unroll
        for (int i = 0; i < 8; i++) bb[i] = *(const bf16x8*)(B + lg * 4096 + (pw * 128 + 16 * i + lr) * 16);
        __builtin_amdgcn_s_setprio(1);
#pragma unroll
        for (int ri = 0; ri < 4; ri++)
#pragma unroll
            for (int ci = 0; ci < 8; ci++) acc[ri][ci] = MFMA(af[ri], bb[ci], acc[ri][ci]);
        __builtin_amdgcn_s_setprio(0);
        __builtin_amdgcn_s_barrier();
    }
    asm volatile("s_waitcnt vmcnt(0)" ::: "memory");

    float sc = var ? alpha[0] : beta[0];
#pragma unroll
    for (int ri = 0; ri < 4; ri++) {
#pragma unroll
        for (int r = 0; r < 4; r++) {
            int m = mbt * 256 + ow * 64 + 16 * ri + 4 * lg + r;
            int pidx = ((m >> 5) + 1) * 34 + (m & 31) + 1;
#pragma unroll
            for (int ci = 0; ci < 8; ci++) {
                int c = cbt * 256 + pw * 128 + 16 * ci + lr;
                float av = acc[ri][ci][r];
                float res;
                if (var == 0) {
                    float xv = bf2f(xT[((size_t)b * 1024 + m) * 512 + c]);
                    res = (1.f - sc) * xv + sc * av;
                } else {
                    float tm = tmA[b * 512 + c];
                    float adv = bf2f(ad[((size_t)b * 512 + c) * 1024 + m]);
                    res = (1.f - sc) * (1024.f * tm - av) + sc * adv;
                }
                catT[((size_t)b * NPADR + pidx) * 1024 + (var ? 512 : 0) + c] = f2bf(res);
            }
        }
    }
}

// ---------------- 3x3 conv: R10 staging + REGISTER frag double-buffer ----------------
// Per phase (one barrier): stage A(p+2); [tap5: stage B(next)]; counted vmcnt
// guaranteeing A(p+1) (and B at tap7+) globally visible; barrier; ISSUE the 8
// ds_reads for phase p+1's fragments; run 16 MFMA on phase p's fragments
// (ds latency hidden under previous phase's MFMA). 4-slot A rotation + B
// double-buffer keep prefetch reads race-free under <=1-phase drift.
// vmcnt per tap (FIFO-derived): taps 5,6 -> vmcnt(4); else vmcnt(1).
__global__ __launch_bounds__(512, 1) void k_conv(const u16* __restrict__ wt, const u16* __restrict__ catT,
                                                 const float* __restrict__ bc, float* __restrict__ out) {
    extern __shared__ __align__(16) char dyn[];
    const int id = blockIdx.x;
    const int xcd = id & 7, j = id >> 3;
    const int obt = j & 3;
    const int pbb = xcd + 8 * (j >> 2);
    const int pbt = pbb & 3, b = pbb >> 2;

    const int tid = threadIdx.x;
    const int l = tid & 63, w = tid >> 6;      // 8 waves
    const int lr = l & 15, lg = l >> 4;
    const int ob = obt * 128;
    const int pb = pbt * 256;
    const int r0 = pbt * 8;
    const int ow = w >> 2, pw = w & 3;
    const u16* catB = catT + (size_t)b * NPADR * 1024 + (size_t)r0 * 34 * 1024;

    auto stageA = [&](int tap, int ck, int slot) {
        char* base = dyn + slot * 8192;
        int row = tid & 127, g = tid >> 7;
        gload16(wt + ((size_t)tap * 512 + ob + row) * 1024 + ck + g * 8,
                base + g * 2048 + row * 16);
    };
    auto stageB = [&](int ck, int sel) {
        char* base = dyn + 32768 + sel * 24576;
#pragma unroll
        for (int it = 0; it < 3; it++) {
            int idx = it * 512 + tid;
            int g = idx / 384;
            int row = idx - g * 384;
            gload16(catB + (size_t)row * 1024 + ck + g * 8,
                    base + g * 6144 + row * 16);
        }
    };

    int aoff[4], rbase[4];
#pragma unroll
    for (int i = 0; i < 4; i++) {
        aoff[i] = lg * 2048 + (ow * 64 + 16 * i + lr) * 16;
        int p = pw * 64 + 16 * i + lr;
        rbase[i] = ((p >> 5) + 1) * 34 + (p & 31) + 1;
    }

    f32x4 acc[4][4];
#pragma unroll
    for (int i = 0; i < 4; i++)
#pragma unroll
        for (int jj = 0; jj < 4; jj++) acc[i][jj] = f32x4{0.f, 0.f, 0.f, 0.f};

    // prologue: A(phase0)->slot0, B(ck0)->buf0, A(phase1)->slot1; full drain; barrier
    stageA(0, 0, 0);
    stageB(0, 0);
    stageA(1, 0, 1);
    asm volatile("s_waitcnt vmcnt(0)" ::: "memory");
    __builtin_amdgcn_s_barrier();

    bf16x8 afc[4], bbc[4], afn[4], bbn[4];
    // fragments for phase 0 (tap 0, drow(0) = -35)
#pragma unroll
    for (int i = 0; i < 4; i++) afc[i] = *(const bf16x8*)(dyn + 0 * 8192 + aoff[i]);
#pragma unroll
    for (int i = 0; i < 4; i++) bbc[i] = *(const bf16x8*)(dyn + 32768 + lg * 6144 + (rbase[i] - 35) * 16);

    int phase = 0;
#pragma unroll 1
    for (int ckI = 0; ckI < 32; ckI++) {
#pragma unroll
        for (int tap = 0; tap < 9; tap++, phase++) {
            // stage A for phase+2
            {
                int t2 = tap + 2;
                int c2 = ckI + (t2 >= 9);
                if (t2 >= 9) t2 -= 9;
                if (c2 >= 32) c2 = 0;  // tail dummy (slot never read)
                stageA(t2, c2 * 32, (phase + 2) & 3);
            }
            if (tap == 5) {
                int cn = ckI + 1;
                stageB((cn >= 32 ? 0 : cn) * 32, cn & 1);
            }
            // guarantee A(phase+1) (and B ordering) globally visible after barrier
            if (tap == 5 || tap == 6) asm volatile("s_waitcnt vmcnt(4)" ::: "memory");
            else                      asm volatile("s_waitcnt vmcnt(1)" ::: "memory");
            __builtin_amdgcn_s_barrier();
            // prefetch fragments for phase+1
            {
                int t1 = tap + 1, c1sel = ckI & 1;
                if (t1 == 9) { t1 = 0; c1sel = (ckI + 1) & 1; }
                const char* An = dyn + ((phase + 1) & 3) * 8192;
                const char* Bn = dyn + 32768 + c1sel * 24576;
                const int drow1 = (t1 / 3 - 1) * 34 + (t1 % 3 - 1);
#pragma unroll
                for (int i = 0; i < 4; i++) afn[i] = *(const bf16x8*)(An + aoff[i]);
#pragma unroll
                for (int i = 0; i < 4; i++) bbn[i] = *(const bf16x8*)(Bn + lg * 6144 + (rbase[i] + drow1) * 16);
            }
            // MFMA with current fragments (loaded last phase; latency fully hidden)
            __builtin_amdgcn_s_setprio(1);
#pragma unroll
            for (int ri = 0; ri < 4; ri++)
#pragma unroll
                for (int ci = 0; ci < 4; ci++) acc[ri][ci] = MFMA(afc[ri], bbc[ci], acc[ri][ci]);
            __builtin_amdgcn_s_setprio(0);
#pragma unroll
            for (int i = 0; i < 4; i++) { afc[i] = afn[i]; bbc[i] = bbn[i]; }
        }
    }
    asm volatile("s_waitcnt vmcnt(0)" ::: "memory");
#pragma unroll
    for (int ri = 0; ri < 4; ri++) {
#pragma unroll
        for (int r = 0; r < 4; r++) {
            int o = ob + ow * 64 + 16 * ri + 4 * lg + r;
            float bias = bc[o];
#pragma unroll
            for (int ci = 0; ci < 4; ci++) {
                int p = pb + pw * 64 + 16 * ci + lr;
                float v = acc[ri][ci][r] + bias;
                v = (v >= 0.f) ? v : 0.2f * v;
                out[((size_t)b * 512 + o) * 1024 + p] = v;
            }
        }
    }
}

// ---------------- launch ----------------
extern "C" void kernel_launch(void* const* d_in, const int* in_sizes, int n_in,
                              void* d_out, int out_size, void* d_ws, size_t ws_size,
                              hipStream_t stream) {
    (void)in_sizes; (void)n_in; (void)out_size; (void)ws_size;
    const float* inp = (const float*)d_in[0];
    const float* x   = (const float*)d_in[1];
    const float* y   = (const float*)d_in[2];
    const float* Wq  = (const float*)d_in[3];
    const float* bq  = (const float*)d_in[4];
    const float* Wk  = (const float*)d_in[5];
    const float* bk  = (const float*)d_in[6];
    const float* Wv  = (const float*)d_in[7];
    const float* bv  = (const float*)d_in[8];
    const float* Wc  = (const float*)d_in[9];
    const float* bc  = (const float*)d_in[10];
    const float* alpha = (const float*)d_in[11];
    const float* beta  = (const float*)d_in[12];
    float* out = (float*)d_out;

    char* ws = (char*)d_ws;
    u16* xT   = (u16*)(ws + OFF_XT);
    u16* yT   = (u16*)(ws + OFF_YT);
    u16* pjx  = (u16*)(ws + OFF_PJX);
    u16* pjy  = (u16*)(ws + OFF_PJY);
    u16* pv   = (u16*)(ws + OFF_PV);
    u16* ad   = (u16*)(ws + OFF_AD);
    u16* attnA = (u16*)(ws + OFF_ATTN);
    u16* attnB = (u16*)(ws + OFF_ATT2);
    u16* catT = (u16*)(ws + OFF_CATT);
    u16* wqk  = (u16*)(ws + OFF_WQK);
    u16* wv   = (u16*)(ws + OFF_WV);
    u16* wt   = (u16*)(ws + OFF_WT);
    float* tmA = (float*)(ws + OFF_TM);

    hipFuncSetAttribute((const void*)k_conv,  hipFuncAttributeMaxDynamicSharedMemorySize, 81920);
    hipFuncSetAttribute((const void*)k_value, hipFuncAttributeMaxDynamicSharedMemorySize, 98304);

    k_prep_w<<<1024, 256, 0, stream>>>(Wq, Wk, Wv, wqk, wv);
    k_prep_wt<<<2048, 256, 0, stream>>>(Wc, wt);
    k_border<<<dim3(132, 16), 256, 0, stream>>>(catT);
    k_stats<<<8192, 256, 0, stream>>>(x, inp, ad, tmA);
    k_transpose<<<dim3(128, 16, 2), 256, 0, stream>>>(x, y, xT, yT);
    k_proj<<<dim3(8, 16, 2), 256, 0, stream>>>(xT, yT, wqk, bq, bk, pjx, pjy);
    k_pv<<<dim3(8, 4, 16), 256, 0, stream>>>(xT, wv, bv, pv);
    k_score<<<dim3(256, 2), 256, 0, stream>>>(pjx, pjy, attnA, attnB);
    k_value<<<256, 512, 98304, stream>>>(attnA, attnB, pv, ad, xT, tmA, alpha, beta, catT);
    k_conv<<<256, 512, 81920, stream>>>(wt, catT, bc, out);
}

// Round 13
// 357.265 us; speedup vs baseline: 1.0735x; 1.0735x over previous
//
#include <hip/hip_runtime.h>

typedef unsigned short u16;
typedef unsigned int u32;

using bf16x8 = __attribute__((ext_vector_type(8))) __bf16;
using f32x4  = __attribute__((ext_vector_type(4))) float;
using u16x4  = __attribute__((ext_vector_type(4))) unsigned short;

__device__ __forceinline__ f32x4 MFMA(bf16x8 a, bf16x8 b, f32x4 c) {
    return __builtin_amdgcn_mfma_f32_16x16x32_bf16(a, b, c, 0, 0, 0);
}

__device__ __forceinline__ u16 f2bf(float f) {
    u32 u = __builtin_bit_cast(u32, f);
    u = (u + 0x7FFFu + ((u >> 16) & 1u)) >> 16;
    return (u16)u;
}
__device__ __forceinline__ float bf2f(u16 h) {
    return __builtin_bit_cast(float, (u32)h << 16);
}

typedef const __attribute__((address_space(1))) unsigned int* gp_t;
typedef __attribute__((address_space(3))) unsigned int* lp_t;

__device__ __forceinline__ void gload16(const void* g, void* l) {
    __builtin_amdgcn_global_load_lds((gp_t)g, (lp_t)l, 16, 0, 0);
}

// ---------------- constants ----------------
#define NPADR  1156   // 34*34

// workspace layout (bytes)
static constexpr size_t OFF_XT   = 0;
static constexpr size_t OFF_YT   = OFF_XT  + (size_t)16*1024*512*2;
static constexpr size_t OFF_PJX  = OFF_YT  + (size_t)16*1024*512*2;
static constexpr size_t OFF_PJY  = OFF_PJX + (size_t)16*1024*128*2;
static constexpr size_t OFF_PV   = OFF_PJY + (size_t)16*1024*128*2;
static constexpr size_t OFF_AD   = OFF_PV  + (size_t)16*512*1024*2;
static constexpr size_t OFF_ATTN = OFF_AD  + (size_t)16*512*1024*2;
static constexpr size_t OFF_ATT2 = OFF_ATTN+ (size_t)16*1024*1024*2;
static constexpr size_t OFF_CATT = OFF_ATT2+ (size_t)16*1024*1024*2;
static constexpr size_t OFF_WQK  = OFF_CATT+ (size_t)16*1156*1024*2;
static constexpr size_t OFF_WV   = OFF_WQK + (size_t)128*512*2;
static constexpr size_t OFF_WT   = OFF_WV  + (size_t)512*512*2;
static constexpr size_t OFF_SA   = OFF_WT  + (size_t)9*512*1024*2;   // srA: [16][1024] f32
static constexpr size_t OFF_TM   = OFF_SA  + (size_t)2*16*512*4;
static constexpr size_t OFF_SB   = OFF_TM  + (size_t)16*512*4;       // srB: [16][1024] f32

// ---------------- weight prep ----------------
__global__ __launch_bounds__(256) void k_prep_w(const float* __restrict__ Wq,
                                                const float* __restrict__ Wk,
                                                const float* __restrict__ Wv,
                                                u16* __restrict__ wqk, u16* __restrict__ wv) {
    int i = blockIdx.x * 256 + threadIdx.x;
    if (i < 128 * 512) {
        float v = (i < 64 * 512) ? Wq[i] : Wk[i - 64 * 512];
        wqk[i] = f2bf(v);
    }
    if (i < 512 * 512) wv[i] = f2bf(Wv[i]);
}

__global__ __launch_bounds__(256) void k_prep_wt(const float* __restrict__ Wc, u16* __restrict__ wt) {
    int e = blockIdx.x * 256 + threadIdx.x;
    const float* src = Wc + (size_t)e * 9;
#pragma unroll
    for (int tap = 0; tap < 9; tap++) wt[(size_t)tap * 524288 + e] = f2bf(src[tap]);
}

// ---------------- zero catT borders ----------------
__global__ __launch_bounds__(256) void k_border(u16* __restrict__ catT) {
    int cell = blockIdx.x, b = blockIdx.y;
    int row, col;
    if (cell < 34)       { row = 0;  col = cell; }
    else if (cell < 68)  { row = 33; col = cell - 34; }
    else if (cell < 100) { row = cell - 68 + 1;  col = 0; }
    else                 { row = cell - 100 + 1; col = 33; }
    u16* dst = catT + ((size_t)b * NPADR + row * 34 + col) * 1024;
    u16x4 z = {0, 0, 0, 0};
    ((u16x4*)dst)[threadIdx.x] = z;
}

// ---------------- stats + fused AdaIN (ad = inp*s + o) ----------------
__global__ __launch_bounds__(256) void k_stats(const float* __restrict__ x, const float* __restrict__ inp,
                                               u16* __restrict__ ad, float* __restrict__ tmA) {
    int row = blockIdx.x;  // b*512+c
    int t = threadIdx.x;
    const float4* xr = (const float4*)(x + (size_t)row * 1024);
    const float4* ir = (const float4*)(inp + (size_t)row * 1024);
    float4 a = xr[t], c = ir[t];
    float s1 = a.x + a.y + a.z + a.w;
    float s2 = a.x * a.x + a.y * a.y + a.z * a.z + a.w * a.w;
    float p1 = c.x + c.y + c.z + c.w;
    float p2 = c.x * c.x + c.y * c.y + c.z * c.z + c.w * c.w;
#pragma unroll
    for (int m = 32; m; m >>= 1) {
        s1 += __shfl_xor(s1, m); s2 += __shfl_xor(s2, m);
        p1 += __shfl_xor(p1, m); p2 += __shfl_xor(p2, m);
    }
    __shared__ float red[4][4];
    __shared__ float bcast[2];
    int wv = t >> 6;
    if ((t & 63) == 0) { red[wv][0] = s1; red[wv][1] = s2; red[wv][2] = p1; red[wv][3] = p2; }
    __syncthreads();
    if (t == 0) {
        s1 = red[0][0] + red[1][0] + red[2][0] + red[3][0];
        s2 = red[0][1] + red[1][1] + red[2][1] + red[3][1];
        p1 = red[0][2] + red[1][2] + red[2][2] + red[3][2];
        p2 = red[0][3] + red[1][3] + red[2][3] + red[3][3];
        float tm = s1 * (1.0f / 1024.0f);
        float ts = sqrtf((s2 - 1024.0f * tm * tm) * (1.0f / 1023.0f) + 1e-5f);
        float im = p1 * (1.0f / 1024.0f);
        float is = sqrtf((p2 - 1024.0f * im * im) * (1.0f / 1023.0f) + 1e-5f);
        float sc = ts / is;
        bcast[0] = sc; bcast[1] = tm - im * sc;
        tmA[row] = tm;
    }
    __syncthreads();
    float sc = bcast[0], of = bcast[1];
    u16x4 r;
    r[0] = f2bf(c.x * sc + of); r[1] = f2bf(c.y * sc + of);
    r[2] = f2bf(c.z * sc + of); r[3] = f2bf(c.w * sc + of);
    ((u16x4*)(ad + (size_t)row * 1024))[t] = r;
}

// ---------------- transpose x,y -> bf16 [n][c] ----------------
__global__ __launch_bounds__(256) void k_transpose(const float* __restrict__ x, const float* __restrict__ y,
                                                   u16* __restrict__ xT, u16* __restrict__ yT) {
    __shared__ float tile[64][65];
    int b = blockIdx.y;
    int ct = blockIdx.x >> 4;
    int nt = blockIdx.x & 15;
    const float* src = blockIdx.z ? y : x;
    u16* dst = blockIdx.z ? yT : xT;
    int c0 = ct * 64, n0 = nt * 64;
    int ln = threadIdx.x & 63, wv = threadIdx.x >> 6;
#pragma unroll
    for (int i = 0; i < 16; i++) {
        int cl = wv + i * 4;
        tile[cl][ln] = src[((size_t)(b * 512 + c0 + cl)) * 1024 + n0 + ln];
    }
    __syncthreads();
#pragma unroll
    for (int i = 0; i < 16; i++) {
        int nl = wv + i * 4;
        dst[((size_t)(b * 1024 + n0 + nl)) * 512 + c0 + ln] = f2bf(tile[ln][nl]);
    }
}

// ---------------- staged 128x128 GEMM core (4-slot, depth-3 counted vmcnt) ----------------
template <int KTOT, int LDA, int LDB>
__device__ __forceinline__ void gemm128(const u16* __restrict__ Aorig, const u16* __restrict__ Borig,
                                        f32x4 (&acc)[4][4]) {
    __shared__ __align__(16) u16 lds[32768];  // A: 4x8KB @0 ; B: 4x8KB @32KB
    constexpr int NT = KTOT / 32;
    const int tid = threadIdx.x;
    const int l = tid & 63, w = tid >> 6;
    const int lr = l & 15, lg = l >> 4;
    const int moff = (w >> 1) * 64, coff = (w & 1) * 64;
    char* ldsb = (char*)lds;
    auto stage = [&](const u16* orig, int ldx, int bufByte) {
#pragma unroll
        for (int it = 0; it < 2; it++) {
            int slot = it * 256 + tid;
            gload16(orig + (size_t)(slot & 127) * ldx + (slot >> 7) * 8,
                    ldsb + bufByte + it * 4096 + w * 1024);
        }
    };
    auto stageT = [&](int t, int s) {
        stage(Aorig + t * 32, LDA, s * 8192);
        stage(Borig + t * 32, LDB, 32768 + s * 8192);
    };
    stageT(0, 0);
    stageT(1, 1);
    stageT(2, 2);
#pragma unroll 1
    for (int q = 0; q < NT; q++) {
        int qq = q + 3; if (qq >= NT) qq -= NT;
        stageT(qq, (q + 3) & 3);
        asm volatile("s_waitcnt vmcnt(12)" ::: "memory");
        __builtin_amdgcn_s_barrier();
        const char* A = ldsb + (q & 3) * 8192;
        const char* B = ldsb + 32768 + (q & 3) * 8192;
        bf16x8 af[4], bb[4];
#pragma unroll
        for (int i = 0; i < 4; i++) af[i] = *(const bf16x8*)(A + lg * 2048 + (moff + 16 * i + lr) * 16);
#pragma unroll
        for (int i = 0; i < 4; i++) bb[i] = *(const bf16x8*)(B + lg * 2048 + (coff + 16 * i + lr) * 16);
        __builtin_amdgcn_s_setprio(1);
#pragma unroll
        for (int ri = 0; ri < 4; ri++)
#pragma unroll
            for (int ci = 0; ci < 4; ci++) acc[ri][ci] = MFMA(af[ri], bb[ci], acc[ri][ci]);
        __builtin_amdgcn_s_setprio(0);
        __builtin_amdgcn_s_barrier();
    }
    asm volatile("s_waitcnt vmcnt(0)" ::: "memory");
}

// ---------------- projections via staged gemm128 ----------------
__global__ __launch_bounds__(256) void k_proj(const u16* __restrict__ xT, const u16* __restrict__ yT,
                                              const u16* __restrict__ wqk, const float* __restrict__ bq,
                                              const float* __restrict__ bk, u16* __restrict__ pjx,
                                              u16* __restrict__ pjy) {
    int b = blockIdx.y;
    const u16* S = blockIdx.z ? yT : xT;
    u16* D = blockIdx.z ? pjy : pjx;
    int nb = blockIdx.x * 128;
    f32x4 acc[4][4];
#pragma unroll
    for (int i = 0; i < 4; i++)
#pragma unroll
        for (int j = 0; j < 4; j++) acc[i][j] = f32x4{0.f, 0.f, 0.f, 0.f};
    gemm128<512, 512, 512>(S + ((size_t)b * 1024 + nb) * 512, wqk, acc);
    int l = threadIdx.x & 63, w = threadIdx.x >> 6;
    int lr = l & 15, lg = l >> 4;
    int moff = (w >> 1) * 64, coff = (w & 1) * 64;
#pragma unroll
    for (int ri = 0; ri < 4; ri++) {
#pragma unroll
        for (int r = 0; r < 4; r++) {
            int n = nb + moff + 16 * ri + 4 * lg + r;
#pragma unroll
            for (int ci = 0; ci < 4; ci++) {
                int cq = coff + 16 * ci + lr;
                float bias = (cq < 64) ? bq[cq] : bk[cq - 64];
                D[((size_t)b * 1024 + n) * 128 + cq] = f2bf(acc[ri][ci][r] + bias);
            }
        }
    }
}

// ---------------- pv = Wv @ x + bv ----------------
__global__ __launch_bounds__(256) void k_pv(const u16* __restrict__ xT, const u16* __restrict__ wv,
                                            const float* __restrict__ bv, u16* __restrict__ pv) {
    int b = blockIdx.z;
    int mb = blockIdx.y * 128;
    int nb = blockIdx.x * 128;
    f32x4 acc[4][4];
#pragma unroll
    for (int i = 0; i < 4; i++)
#pragma unroll
        for (int j = 0; j < 4; j++) acc[i][j] = f32x4{0.f, 0.f, 0.f, 0.f};
    gemm128<512, 512, 512>(wv + (size_t)mb * 512, xT + ((size_t)b * 1024 + nb) * 512, acc);
    int l = threadIdx.x & 63, w = threadIdx.x >> 6;
    int lr = l & 15, lg = l >> 4;
    int moff = (w >> 1) * 64, coff = (w & 1) * 64;
#pragma unroll
    for (int ri = 0; ri < 4; ri++) {
#pragma unroll
        for (int r = 0; r < 4; r++) {
            int co = mb + moff + 16 * ri + 4 * lg + r;
            float bias = bv[co];
#pragma unroll
            for (int ci = 0; ci < 4; ci++) {
                int n = nb + coff + 16 * ci + lr;
                pv[((size_t)b * 512 + co) * 1024 + n] = f2bf(acc[ri][ci][r] + bias);
            }
        }
    }
}

// ---------------- score: SINGLE pass, store unnormalized exp + per-row inv ----------------
__global__ __launch_bounds__(256) void k_score(const u16* __restrict__ pjx, const u16* __restrict__ pjy,
                                               u16* __restrict__ attnA, u16* __restrict__ attnB,
                                               float* __restrict__ srA, float* __restrict__ srB) {
    const u16* qT = blockIdx.y ? pjy : pjx;
    const u16* kT = blockIdx.y ? pjx : pjy;
    u16* attn = blockIdx.y ? attnB : attnA;
    float* sr = blockIdx.y ? srB : srA;
    int g = blockIdx.x * 4 + (threadIdx.x >> 6);
    int b = g >> 6, rb = g & 63;
    int l = threadIdx.x & 63, lr = l & 15, lg = l >> 4;
    int mb = rb * 16;
    const u16* qbase = qT + ((size_t)b * 1024 + mb + lr) * 128 + lg * 8;
    bf16x8 a0 = *(const bf16x8*)(qbase);
    bf16x8 a1 = *(const bf16x8*)(qbase + 32);
    const u16* kbase = kT + ((size_t)b * 1024 + lr) * 128 + 64 + lg * 8;
    f32x4 zero = {0.f, 0.f, 0.f, 0.f};
    float ref[4], srun[4];
    {
        bf16x8 b0 = *(const bf16x8*)(kbase);
        bf16x8 b1 = *(const bf16x8*)(kbase + 32);
        f32x4 acc = zero;
        acc = MFMA(a0, b0, acc);
        acc = MFMA(a1, b1, acc);
#pragma unroll
        for (int r = 0; r < 4; r++) {
            ref[r] = __shfl(acc[r] * 0.125f, l & 0x30);   // column-0 score of this row
            srun[r] = 0.f;
        }
    }
    for (int cf = 0; cf < 64; cf++) {
        bf16x8 b0 = *(const bf16x8*)(kbase + (size_t)cf * 16 * 128);
        bf16x8 b1 = *(const bf16x8*)(kbase + (size_t)cf * 16 * 128 + 32);
        f32x4 acc = zero;
        acc = MFMA(a0, b0, acc);
        acc = MFMA(a1, b1, acc);
#pragma unroll
        for (int r = 0; r < 4; r++) {
            float e = __expf(acc[r] * 0.125f - ref[r]);
            srun[r] += e;
            attn[((size_t)b * 1024 + mb + 4 * lg + r) * 1024 + cf * 16 + lr] = f2bf(e);
        }
    }
#pragma unroll
    for (int r = 0; r < 4; r++) {
#pragma unroll
        for (int m = 1; m < 16; m <<= 1) srun[r] += __shfl_xor(srun[r], m);
    }
    if (lr == 0) {
#pragma unroll
        for (int r = 0; r < 4; r++) sr[b * 1024 + mb + 4 * lg + r] = 1.0f / srun[r];
    }
}

// ---------------- value GEMMs: 256x256 block tile, 8 waves of 64x128 ----------------
// A-operand is UNNORMALIZED exp; epilogue multiplies by inv[m] (from k_score).
__global__ __launch_bounds__(512, 2) void k_value(const u16* __restrict__ attnA, const u16* __restrict__ attnB,
                                                  const u16* __restrict__ pv, const u16* __restrict__ ad,
                                                  const u16* __restrict__ xT, const float* __restrict__ tmA,
                                                  const float* __restrict__ srA, const float* __restrict__ srB,
                                                  const float* __restrict__ alpha, const float* __restrict__ beta,
                                                  u16* __restrict__ catT) {
    extern __shared__ __align__(16) char dyn[];
    const int id = blockIdx.x;
    const int xcd = id & 7, j = id >> 3;
    const int z = xcd + 8 * (j & 3);
    const int tile = j >> 2;
    const int mbt = tile & 3, cbt = tile >> 2;
    const int b = z & 15, var = z >> 4;
    const u16* Aorig = (var ? attnB : attnA) + ((size_t)b * 1024 + mbt * 256) * 1024;
    const u16* Borig = (var ? ad : pv) + ((size_t)b * 512 + cbt * 256) * 1024;
    const float* sr = (var ? srB : srA) + b * 1024;

    const int tid = threadIdx.x;
    const int l = tid & 63, w = tid >> 6;
    const int lr = l & 15, lg = l >> 4;
    const int ow = w >> 1, pw = w & 1;

    auto stageT = [&](int t, int s) {
        char* base = dyn + s * 32768;
#pragma unroll
        for (int it = 0; it < 2; it++) {
            int idx = it * 512 + tid;
            int row = idx & 255, g = idx >> 8;
            gload16(Aorig + (size_t)row * 1024 + t * 32 + g * 8, base + g * 4096 + row * 16);
        }
#pragma unroll
        for (int it = 0; it < 2; it++) {
            int idx = it * 512 + tid;
            int row = idx & 255, g = idx >> 8;
            gload16(Borig + (size_t)row * 1024 + t * 32 + g * 8, base + 16384 + g * 4096 + row * 16);
        }
    };

    f32x4 acc[4][8];
#pragma unroll
    for (int i = 0; i < 4; i++)
#pragma unroll
        for (int jj = 0; jj < 8; jj++) acc[i][jj] = f32x4{0.f, 0.f, 0.f, 0.f};

    stageT(0, 0);
    stageT(1, 1);
#pragma unroll 1
    for (int q = 0; q < 32; q++) {
        int qq = q + 2; if (qq >= 32) qq -= 32;
        stageT(qq, (q + 2) % 3);
        asm volatile("s_waitcnt vmcnt(8)" ::: "memory");
        __builtin_amdgcn_s_barrier();
        const char* A = dyn + (q % 3) * 32768;
        const char* B = A + 16384;
        bf16x8 af[4], bb[8];
#pragma unroll
        for (int i = 0; i < 4; i++) af[i] = *(const bf16x8*)(A + lg * 4096 + (ow * 64 + 16 * i + lr) * 16);
#pragma unroll
        for (int i = 0; i < 8; i++) bb[i] = *(const bf16x8*)(B + lg * 4096 + (pw * 128 + 16 * i + lr) * 16);
        __builtin_amdgcn_s_setprio(1);
#pragma unroll
        for (int ri = 0; ri < 4; ri++)
#pragma unroll
            for (int ci = 0; ci < 8; ci++) acc[ri][ci] = MFMA(af[ri], bb[ci], acc[ri][ci]);
        __builtin_amdgcn_s_setprio(0);
        __builtin_amdgcn_s_barrier();
    }
    asm volatile("s_waitcnt vmcnt(0)" ::: "memory");

    float sc = var ? alpha[0] : beta[0];
#pragma unroll
    for (int ri = 0; ri < 4; ri++) {
#pragma unroll
        for (int r = 0; r < 4; r++) {
            int m = mbt * 256 + ow * 64 + 16 * ri + 4 * lg + r;
            int pidx = ((m >> 5) + 1) * 34 + (m & 31) + 1;
            float ivm = sr[m];
#pragma unroll
            for (int ci = 0; ci < 8; ci++) {
                int c = cbt * 256 + pw * 128 + 16 * ci + lr;
                float av = acc[ri][ci][r] * ivm;
                float res;
                if (var == 0) {
                    float xv = bf2f(xT[((size_t)b * 1024 + m) * 512 + c]);
                    res = (1.f - sc) * xv + sc * av;
                } else {
                    float tm = tmA[b * 512 + c];
                    float adv = bf2f(ad[((size_t)b * 512 + c) * 1024 + m]);
                    res = (1.f - sc) * (1024.f * tm - av) + sc * adv;
                }
                catT[((size_t)b * NPADR + pidx) * 1024 + (var ? 512 : 0) + c] = f2bf(res);
            }
        }
    }
}

// ---------------- 3x3 conv: K=64 phases (2 tap-steps/phase), 144 phases ----------------
// 512 thr, block 128o x 256p, grid 256, XCD swizzle.
// LDS 122880B: A 9 slots x 8KB @0 (slot = tap_step % 9  -- cc-invariant since
// 18 % 9 == 0; FIX of R12's &7 bug); B 2 x 24KB @73728.
// Per phase u (compile-time unrolled, 9 phases = 2 ck): stage 2 A tap-steps
// (4 ahead) (+B at u=2,6); counted vmcnt {4,4,7,7,4,4,7,7,7} (FIFO-verified);
// one barrier; 16 ds_read_b128; 32 MFMA. Slot write/read distance 3..7 mod 9
// under <=1-phase drift -> race-free with the single barrier.
__global__ __launch_bounds__(512, 1) void k_conv(const u16* __restrict__ wt, const u16* __restrict__ catT,
                                                 const float* __restrict__ bc, float* __restrict__ out) {
    extern __shared__ __align__(16) char dyn[];
    const int id = blockIdx.x;
    const int xcd = id & 7, j = id >> 3;
    const int obt = j & 3;
    const int pbb = xcd + 8 * (j >> 2);
    const int pbt = pbb & 3, b = pbb >> 2;

    const int tid = threadIdx.x;
    const int l = tid & 63, w = tid >> 6;      // 8 waves
    const int lr = l & 15, lg = l >> 4;
    const int ob = obt * 128;
    const int pb = pbt * 256;
    const int r0 = pbt * 8;
    const int ow = w >> 2, pw = w & 3;
    const u16* catB = catT + (size_t)b * NPADR * 1024 + (size_t)r0 * 34 * 1024;

    auto stageA = [&](int tap, int ckoff, int slot) {
        char* base = dyn + slot * 8192;
        int row = tid & 127, g = tid >> 7;
        gload16(wt + ((size_t)tap * 512 + ob + row) * 1024 + ckoff + g * 8,
                base + g * 2048 + row * 16);
    };
    auto stageB = [&](int ckoff, int sel) {
        char* base = dyn + 73728 + sel * 24576;
#pragma unroll
        for (int it = 0; it < 3; it++) {
            int idx = it * 512 + tid;
            int g = idx / 384;
            int row = idx - g * 384;
            gload16(catB + (size_t)row * 1024 + ckoff + g * 8,
                    base + g * 6144 + row * 16);
        }
    };

    int aoff[4], rbase[4];
#pragma unroll
    for (int i = 0; i < 4; i++) {
        aoff[i] = lg * 2048 + (ow * 64 + 16 * i + lr) * 16;
        int p = pw * 64 + 16 * i + lr;
        rbase[i] = ((p >> 5) + 1) * 34 + (p & 31) + 1;
    }

    f32x4 acc[4][4];
#pragma unroll
    for (int i = 0; i < 4; i++)
#pragma unroll
        for (int jj = 0; jj < 4; jj++) acc[i][jj] = f32x4{0.f, 0.f, 0.f, 0.f};

    // prologue FIFO: A(step0), A(step1), B(ck0)x3, A(step2), A(step3) -> slots 0,1,2,3
    stageA(0, 0, 0);
    stageA(1, 0, 1);
    stageB(0, 0);
    stageA(2, 0, 2);
    stageA(3, 0, 3);

    // compile-time tables: staged tap-steps s0=2u+4, s1=2u+5 within the 18-step block
    static constexpr int TAPS0[9] = {4, 6, 8, 1, 3, 5, 7, 0, 2};   // (2u+4) % 9
    static constexpr int CKD0[9]  = {0, 0, 0, 1, 1, 1, 1, 2, 2};   // (2u+4) / 9
    static constexpr int TAPS1[9] = {5, 7, 0, 2, 4, 6, 8, 1, 3};   // (2u+5) % 9
    static constexpr int CKD1[9]  = {0, 0, 1, 1, 1, 1, 1, 2, 2};   // (2u+5) / 9
    static constexpr int DROW0[9] = {-35, -33, 0, 33, 35, -34, -1, 1, 34};   // drow(tap(2u))
    static constexpr int DROW1[9] = {-34, -1, 1, 34, -35, -33, 0, 33, 35};   // drow(tap(2u+1))
    // slot tables (tap_step % 9): compute slots for steps 2u, 2u+1; stage slots for 2u+4, 2u+5
    static constexpr int SLC0[9] = {0, 2, 4, 6, 8, 1, 3, 5, 7};    // (2u) % 9
    static constexpr int SLC1[9] = {1, 3, 5, 7, 0, 2, 4, 6, 8};    // (2u+1) % 9
    static constexpr int SLS0[9] = {4, 6, 8, 1, 3, 5, 7, 0, 2};    // (2u+4) % 9
    static constexpr int SLS1[9] = {5, 7, 0, 2, 4, 6, 8, 1, 3};    // (2u+5) % 9

#pragma unroll 1
    for (int cc = 0; cc < 16; cc++) {
#pragma unroll
        for (int u = 0; u < 9; u++) {
            {
                int ck = 2 * cc + CKD0[u];
                stageA(TAPS0[u], (ck >= 32 ? 0 : ck) * 32, SLS0[u]);
            }
            {
                int ck = 2 * cc + CKD1[u];
                stageA(TAPS1[u], (ck >= 32 ? 0 : ck) * 32, SLS1[u]);
            }
            if (u == 2) { int cn = 2 * cc + 1; stageB(cn * 32, 1); }
            if (u == 6) { int cn = 2 * cc + 2; stageB((cn >= 32 ? 0 : cn) * 32, 0); }
            if (u == 2 || u == 3 || u >= 6) asm volatile("s_waitcnt vmcnt(7)" ::: "memory");
            else                            asm volatile("s_waitcnt vmcnt(4)" ::: "memory");
            __builtin_amdgcn_s_barrier();
            const char* A0 = dyn + SLC0[u] * 8192;
            const char* A1 = dyn + SLC1[u] * 8192;
            const char* B0 = dyn + 73728 + ((u >= 5) ? 24576 : 0);
            const char* B1 = dyn + 73728 + ((u >= 4) ? 24576 : 0);
            bf16x8 af0[4], bb0[4], af1[4], bb1[4];
#pragma unroll
            for (int i = 0; i < 4; i++) {
                af0[i] = *(const bf16x8*)(A0 + aoff[i]);
                bb0[i] = *(const bf16x8*)(B0 + lg * 6144 + (rbase[i] + DROW0[u]) * 16);
            }
#pragma unroll
            for (int i = 0; i < 4; i++) {
                af1[i] = *(const bf16x8*)(A1 + aoff[i]);
                bb1[i] = *(const bf16x8*)(B1 + lg * 6144 + (rbase[i] + DROW1[u]) * 16);
            }
            __builtin_amdgcn_s_setprio(1);
#pragma unroll
            for (int ri = 0; ri < 4; ri++)
#pragma unroll
                for (int ci = 0; ci < 4; ci++) acc[ri][ci] = MFMA(af0[ri], bb0[ci], acc[ri][ci]);
#pragma unroll
            for (int ri = 0; ri < 4; ri++)
#pragma unroll
                for (int ci = 0; ci < 4; ci++) acc[ri][ci] = MFMA(af1[ri], bb1[ci], acc[ri][ci]);
            __builtin_amdgcn_s_setprio(0);
        }
    }
    asm volatile("s_waitcnt vmcnt(0)" ::: "memory");
#pragma unroll
    for (int ri = 0; ri < 4; ri++) {
#pragma unroll
        for (int r = 0; r < 4; r++) {
            int o = ob + ow * 64 + 16 * ri + 4 * lg + r;
            float bias = bc[o];
#pragma unroll
            for (int ci = 0; ci < 4; ci++) {
                int p = pb + pw * 64 + 16 * ci + lr;
                float v = acc[ri][ci][r] + bias;
                v = (v >= 0.f) ? v : 0.2f * v;
                out[((size_t)b * 512 + o) * 1024 + p] = v;
            }
        }
    }
}

// ---------------- launch ----------------
extern "C" void kernel_launch(void* const* d_in, const int* in_sizes, int n_in,
                              void* d_out, int out_size, void* d_ws, size_t ws_size,
                              hipStream_t stream) {
    (void)in_sizes; (void)n_in; (void)out_size; (void)ws_size;
    const float* inp = (const float*)d_in[0];
    const float* x   = (const float*)d_in[1];
    const float* y   = (const float*)d_in[2];
    const float* Wq  = (const float*)d_in[3];
    const float* bq  = (const float*)d_in[4];
    const float* Wk  = (const float*)d_in[5];
    const float* bk  = (const float*)d_in[6];
    const float* Wv  = (const float*)d_in[7];
    const float* bv  = (const float*)d_in[8];
    const float* Wc  = (const float*)d_in[9];
    const float* bc  = (const float*)d_in[10];
    const float* alpha = (const float*)d_in[11];
    const float* beta  = (const float*)d_in[12];
    float* out = (float*)d_out;

    char* ws = (char*)d_ws;
    u16* xT   = (u16*)(ws + OFF_XT);
    u16* yT   = (u16*)(ws + OFF_YT);
    u16* pjx  = (u16*)(ws + OFF_PJX);
    u16* pjy  = (u16*)(ws + OFF_PJY);
    u16* pv   = (u16*)(ws + OFF_PV);
    u16* ad   = (u16*)(ws + OFF_AD);
    u16* attnA = (u16*)(ws + OFF_ATTN);
    u16* attnB = (u16*)(ws + OFF_ATT2);
    u16* catT = (u16*)(ws + OFF_CATT);
    u16* wqk  = (u16*)(ws + OFF_WQK);
    u16* wv   = (u16*)(ws + OFF_WV);
    u16* wt   = (u16*)(ws + OFF_WT);
    float* srA = (float*)(ws + OFF_SA);
    float* tmA = (float*)(ws + OFF_TM);
    float* srB = (float*)(ws + OFF_SB);

    hipFuncSetAttribute((const void*)k_conv,  hipFuncAttributeMaxDynamicSharedMemorySize, 122880);
    hipFuncSetAttribute((const void*)k_value, hipFuncAttributeMaxDynamicSharedMemorySize, 98304);

    k_prep_w<<<1024, 256, 0, stream>>>(Wq, Wk, Wv, wqk, wv);
    k_prep_wt<<<2048, 256, 0, stream>>>(Wc, wt);
    k_border<<<dim3(132, 16), 256, 0, stream>>>(catT);
    k_stats<<<8192, 256, 0, stream>>>(x, inp, ad, tmA);
    k_transpose<<<dim3(128, 16, 2), 256, 0, stream>>>(x, y, xT, yT);
    k_proj<<<dim3(8, 16, 2), 256, 0, stream>>>(xT, yT, wqk, bq, bk, pjx, pjy);
    k_pv<<<dim3(8, 4, 16), 256, 0, stream>>>(xT, wv, bv, pv);
    k_score<<<dim3(256, 2), 256, 0, stream>>>(pjx, pjy, attnA, attnB, srA, srB);
    k_value<<<256, 512, 98304, stream>>>(attnA, attnB, pv, ad, xT, tmA, srA, srB, alpha, beta, catT);
    k_conv<<<256, 512, 122880, stream>>>(wt, catT, bc, out);
}

// Round 14
// 356.572 us; speedup vs baseline: 1.0756x; 1.0019x over previous
//
#include <hip/hip_runtime.h>

typedef unsigned short u16;
typedef unsigned int u32;

using bf16x8 = __attribute__((ext_vector_type(8))) __bf16;
using f32x4  = __attribute__((ext_vector_type(4))) float;
using u16x4  = __attribute__((ext_vector_type(4))) unsigned short;

__device__ __forceinline__ f32x4 MFMA(bf16x8 a, bf16x8 b, f32x4 c) {
    return __builtin_amdgcn_mfma_f32_16x16x32_bf16(a, b, c, 0, 0, 0);
}

__device__ __forceinline__ u16 f2bf(float f) {
    u32 u = __builtin_bit_cast(u32, f);
    u = (u + 0x7FFFu + ((u >> 16) & 1u)) >> 16;
    return (u16)u;
}
__device__ __forceinline__ float bf2f(u16 h) {
    return __builtin_bit_cast(float, (u32)h << 16);
}

typedef const __attribute__((address_space(1))) unsigned int* gp_t;
typedef __attribute__((address_space(3))) unsigned int* lp_t;

__device__ __forceinline__ void gload16(const void* g, void* l) {
    __builtin_amdgcn_global_load_lds((gp_t)g, (lp_t)l, 16, 0, 0);
}

// ---------------- constants ----------------
#define NPADR  1156   // 34*34

// workspace layout (bytes)
static constexpr size_t OFF_XT   = 0;
static constexpr size_t OFF_YT   = OFF_XT  + (size_t)16*1024*512*2;
static constexpr size_t OFF_PJX  = OFF_YT  + (size_t)16*1024*512*2;
static constexpr size_t OFF_PJY  = OFF_PJX + (size_t)16*1024*128*2;
static constexpr size_t OFF_PV   = OFF_PJY + (size_t)16*1024*128*2;
static constexpr size_t OFF_AD   = OFF_PV  + (size_t)16*512*1024*2;
static constexpr size_t OFF_ATTN = OFF_AD  + (size_t)16*512*1024*2;
static constexpr size_t OFF_ATT2 = OFF_ATTN+ (size_t)16*1024*1024*2;
static constexpr size_t OFF_CATT = OFF_ATT2+ (size_t)16*1024*1024*2;
static constexpr size_t OFF_WQK  = OFF_CATT+ (size_t)16*1156*1024*2;
static constexpr size_t OFF_WV   = OFF_WQK + (size_t)128*512*2;
static constexpr size_t OFF_WT   = OFF_WV  + (size_t)512*512*2;
static constexpr size_t OFF_SA   = OFF_WT  + (size_t)9*512*1024*2;   // srA: [16][1024] f32
static constexpr size_t OFF_TM   = OFF_SA  + (size_t)2*16*512*4;
static constexpr size_t OFF_SB   = OFF_TM  + (size_t)16*512*4;       // srB: [16][1024] f32

// ---------------- weight prep ----------------
__global__ __launch_bounds__(256) void k_prep_w(const float* __restrict__ Wq,
                                                const float* __restrict__ Wk,
                                                const float* __restrict__ Wv,
                                                u16* __restrict__ wqk, u16* __restrict__ wv) {
    int i = blockIdx.x * 256 + threadIdx.x;
    if (i < 128 * 512) {
        float v = (i < 64 * 512) ? Wq[i] : Wk[i - 64 * 512];
        wqk[i] = f2bf(v);
    }
    if (i < 512 * 512) wv[i] = f2bf(Wv[i]);
}

__global__ __launch_bounds__(256) void k_prep_wt(const float* __restrict__ Wc, u16* __restrict__ wt) {
    int e = blockIdx.x * 256 + threadIdx.x;
    const float* src = Wc + (size_t)e * 9;
#pragma unroll
    for (int tap = 0; tap < 9; tap++) wt[(size_t)tap * 524288 + e] = f2bf(src[tap]);
}

// ---------------- zero catT borders ----------------
__global__ __launch_bounds__(256) void k_border(u16* __restrict__ catT) {
    int cell = blockIdx.x, b = blockIdx.y;
    int row, col;
    if (cell < 34)       { row = 0;  col = cell; }
    else if (cell < 68)  { row = 33; col = cell - 34; }
    else if (cell < 100) { row = cell - 68 + 1;  col = 0; }
    else                 { row = cell - 100 + 1; col = 33; }
    u16* dst = catT + ((size_t)b * NPADR + row * 34 + col) * 1024;
    u16x4 z = {0, 0, 0, 0};
    ((u16x4*)dst)[threadIdx.x] = z;
}

// ---------------- stats + fused AdaIN (ad = inp*s + o) ----------------
__global__ __launch_bounds__(256) void k_stats(const float* __restrict__ x, const float* __restrict__ inp,
                                               u16* __restrict__ ad, float* __restrict__ tmA) {
    int row = blockIdx.x;  // b*512+c
    int t = threadIdx.x;
    const float4* xr = (const float4*)(x + (size_t)row * 1024);
    const float4* ir = (const float4*)(inp + (size_t)row * 1024);
    float4 a = xr[t], c = ir[t];
    float s1 = a.x + a.y + a.z + a.w;
    float s2 = a.x * a.x + a.y * a.y + a.z * a.z + a.w * a.w;
    float p1 = c.x + c.y + c.z + c.w;
    float p2 = c.x * c.x + c.y * c.y + c.z * c.z + c.w * c.w;
#pragma unroll
    for (int m = 32; m; m >>= 1) {
        s1 += __shfl_xor(s1, m); s2 += __shfl_xor(s2, m);
        p1 += __shfl_xor(p1, m); p2 += __shfl_xor(p2, m);
    }
    __shared__ float red[4][4];
    __shared__ float bcast[2];
    int wv = t >> 6;
    if ((t & 63) == 0) { red[wv][0] = s1; red[wv][1] = s2; red[wv][2] = p1; red[wv][3] = p2; }
    __syncthreads();
    if (t == 0) {
        s1 = red[0][0] + red[1][0] + red[2][0] + red[3][0];
        s2 = red[0][1] + red[1][1] + red[2][1] + red[3][1];
        p1 = red[0][2] + red[1][2] + red[2][2] + red[3][2];
        p2 = red[0][3] + red[1][3] + red[2][3] + red[3][3];
        float tm = s1 * (1.0f / 1024.0f);
        float ts = sqrtf((s2 - 1024.0f * tm * tm) * (1.0f / 1023.0f) + 1e-5f);
        float im = p1 * (1.0f / 1024.0f);
        float is = sqrtf((p2 - 1024.0f * im * im) * (1.0f / 1023.0f) + 1e-5f);
        float sc = ts / is;
        bcast[0] = sc; bcast[1] = tm - im * sc;
        tmA[row] = tm;
    }
    __syncthreads();
    float sc = bcast[0], of = bcast[1];
    u16x4 r;
    r[0] = f2bf(c.x * sc + of); r[1] = f2bf(c.y * sc + of);
    r[2] = f2bf(c.z * sc + of); r[3] = f2bf(c.w * sc + of);
    ((u16x4*)(ad + (size_t)row * 1024))[t] = r;
}

// ---------------- transpose x,y -> bf16 [n][c] ----------------
__global__ __launch_bounds__(256) void k_transpose(const float* __restrict__ x, const float* __restrict__ y,
                                                   u16* __restrict__ xT, u16* __restrict__ yT) {
    __shared__ float tile[64][65];
    int b = blockIdx.y;
    int ct = blockIdx.x >> 4;
    int nt = blockIdx.x & 15;
    const float* src = blockIdx.z ? y : x;
    u16* dst = blockIdx.z ? yT : xT;
    int c0 = ct * 64, n0 = nt * 64;
    int ln = threadIdx.x & 63, wv = threadIdx.x >> 6;
#pragma unroll
    for (int i = 0; i < 16; i++) {
        int cl = wv + i * 4;
        tile[cl][ln] = src[((size_t)(b * 512 + c0 + cl)) * 1024 + n0 + ln];
    }
    __syncthreads();
#pragma unroll
    for (int i = 0; i < 16; i++) {
        int nl = wv + i * 4;
        dst[((size_t)(b * 1024 + n0 + nl)) * 512 + c0 + ln] = f2bf(tile[ln][nl]);
    }
}

// ---------------- staged 128x128 GEMM core (4-slot, depth-3 counted vmcnt) ----------------
template <int KTOT, int LDA, int LDB>
__device__ __forceinline__ void gemm128(const u16* __restrict__ Aorig, const u16* __restrict__ Borig,
                                        f32x4 (&acc)[4][4]) {
    __shared__ __align__(16) u16 lds[32768];  // A: 4x8KB @0 ; B: 4x8KB @32KB
    constexpr int NT = KTOT / 32;
    const int tid = threadIdx.x;
    const int l = tid & 63, w = tid >> 6;
    const int lr = l & 15, lg = l >> 4;
    const int moff = (w >> 1) * 64, coff = (w & 1) * 64;
    char* ldsb = (char*)lds;
    auto stage = [&](const u16* orig, int ldx, int bufByte) {
#pragma unroll
        for (int it = 0; it < 2; it++) {
            int slot = it * 256 + tid;
            gload16(orig + (size_t)(slot & 127) * ldx + (slot >> 7) * 8,
                    ldsb + bufByte + it * 4096 + w * 1024);
        }
    };
    auto stageT = [&](int t, int s) {
        stage(Aorig + t * 32, LDA, s * 8192);
        stage(Borig + t * 32, LDB, 32768 + s * 8192);
    };
    stageT(0, 0);
    stageT(1, 1);
    stageT(2, 2);
#pragma unroll 1
    for (int q = 0; q < NT; q++) {
        int qq = q + 3; if (qq >= NT) qq -= NT;
        stageT(qq, (q + 3) & 3);
        asm volatile("s_waitcnt vmcnt(12)" ::: "memory");
        __builtin_amdgcn_s_barrier();
        const char* A = ldsb + (q & 3) * 8192;
        const char* B = ldsb + 32768 + (q & 3) * 8192;
        bf16x8 af[4], bb[4];
#pragma unroll
        for (int i = 0; i < 4; i++) af[i] = *(const bf16x8*)(A + lg * 2048 + (moff + 16 * i + lr) * 16);
#pragma unroll
        for (int i = 0; i < 4; i++) bb[i] = *(const bf16x8*)(B + lg * 2048 + (coff + 16 * i + lr) * 16);
        __builtin_amdgcn_s_setprio(1);
#pragma unroll
        for (int ri = 0; ri < 4; ri++)
#pragma unroll
            for (int ci = 0; ci < 4; ci++) acc[ri][ci] = MFMA(af[ri], bb[ci], acc[ri][ci]);
        __builtin_amdgcn_s_setprio(0);
        __builtin_amdgcn_s_barrier();
    }
    asm volatile("s_waitcnt vmcnt(0)" ::: "memory");
}

// ---------------- projections via staged gemm128 ----------------
__global__ __launch_bounds__(256) void k_proj(const u16* __restrict__ xT, const u16* __restrict__ yT,
                                              const u16* __restrict__ wqk, const float* __restrict__ bq,
                                              const float* __restrict__ bk, u16* __restrict__ pjx,
                                              u16* __restrict__ pjy) {
    int b = blockIdx.y;
    const u16* S = blockIdx.z ? yT : xT;
    u16* D = blockIdx.z ? pjy : pjx;
    int nb = blockIdx.x * 128;
    f32x4 acc[4][4];
#pragma unroll
    for (int i = 0; i < 4; i++)
#pragma unroll
        for (int j = 0; j < 4; j++) acc[i][j] = f32x4{0.f, 0.f, 0.f, 0.f};
    gemm128<512, 512, 512>(S + ((size_t)b * 1024 + nb) * 512, wqk, acc);
    int l = threadIdx.x & 63, w = threadIdx.x >> 6;
    int lr = l & 15, lg = l >> 4;
    int moff = (w >> 1) * 64, coff = (w & 1) * 64;
#pragma unroll
    for (int ri = 0; ri < 4; ri++) {
#pragma unroll
        for (int r = 0; r < 4; r++) {
            int n = nb + moff + 16 * ri + 4 * lg + r;
#pragma unroll
            for (int ci = 0; ci < 4; ci++) {
                int cq = coff + 16 * ci + lr;
                float bias = (cq < 64) ? bq[cq] : bk[cq - 64];
                D[((size_t)b * 1024 + n) * 128 + cq] = f2bf(acc[ri][ci][r] + bias);
            }
        }
    }
}

// ---------------- pv = Wv @ x + bv ----------------
__global__ __launch_bounds__(256) void k_pv(const u16* __restrict__ xT, const u16* __restrict__ wv,
                                            const float* __restrict__ bv, u16* __restrict__ pv) {
    int b = blockIdx.z;
    int mb = blockIdx.y * 128;
    int nb = blockIdx.x * 128;
    f32x4 acc[4][4];
#pragma unroll
    for (int i = 0; i < 4; i++)
#pragma unroll
        for (int j = 0; j < 4; j++) acc[i][j] = f32x4{0.f, 0.f, 0.f, 0.f};
    gemm128<512, 512, 512>(wv + (size_t)mb * 512, xT + ((size_t)b * 1024 + nb) * 512, acc);
    int l = threadIdx.x & 63, w = threadIdx.x >> 6;
    int lr = l & 15, lg = l >> 4;
    int moff = (w >> 1) * 64, coff = (w & 1) * 64;
#pragma unroll
    for (int ri = 0; ri < 4; ri++) {
#pragma unroll
        for (int r = 0; r < 4; r++) {
            int co = mb + moff + 16 * ri + 4 * lg + r;
            float bias = bv[co];
#pragma unroll
            for (int ci = 0; ci < 4; ci++) {
                int n = nb + coff + 16 * ci + lr;
                pv[((size_t)b * 512 + co) * 1024 + n] = f2bf(acc[ri][ci][r] + bias);
            }
        }
    }
}

// ---------------- score: SINGLE pass, store unnormalized exp + per-row inv ----------------
__global__ __launch_bounds__(256) void k_score(const u16* __restrict__ pjx, const u16* __restrict__ pjy,
                                               u16* __restrict__ attnA, u16* __restrict__ attnB,
                                               float* __restrict__ srA, float* __restrict__ srB) {
    const u16* qT = blockIdx.y ? pjy : pjx;
    const u16* kT = blockIdx.y ? pjx : pjy;
    u16* attn = blockIdx.y ? attnB : attnA;
    float* sr = blockIdx.y ? srB : srA;
    int g = blockIdx.x * 4 + (threadIdx.x >> 6);
    int b = g >> 6, rb = g & 63;
    int l = threadIdx.x & 63, lr = l & 15, lg = l >> 4;
    int mb = rb * 16;
    const u16* qbase = qT + ((size_t)b * 1024 + mb + lr) * 128 + lg * 8;
    bf16x8 a0 = *(const bf16x8*)(qbase);
    bf16x8 a1 = *(const bf16x8*)(qbase + 32);
    const u16* kbase = kT + ((size_t)b * 1024 + lr) * 128 + 64 + lg * 8;
    f32x4 zero = {0.f, 0.f, 0.f, 0.f};
    float ref[4], srun[4];
    {
        bf16x8 b0 = *(const bf16x8*)(kbase);
        bf16x8 b1 = *(const bf16x8*)(kbase + 32);
        f32x4 acc = zero;
        acc = MFMA(a0, b0, acc);
        acc = MFMA(a1, b1, acc);
#pragma unroll
        for (int r = 0; r < 4; r++) {
            ref[r] = __shfl(acc[r] * 0.125f, l & 0x30);   // column-0 score of this row
            srun[r] = 0.f;
        }
    }
    for (int cf = 0; cf < 64; cf++) {
        bf16x8 b0 = *(const bf16x8*)(kbase + (size_t)cf * 16 * 128);
        bf16x8 b1 = *(const bf16x8*)(kbase + (size_t)cf * 16 * 128 + 32);
        f32x4 acc = zero;
        acc = MFMA(a0, b0, acc);
        acc = MFMA(a1, b1, acc);
#pragma unroll
        for (int r = 0; r < 4; r++) {
            float e = __expf(acc[r] * 0.125f - ref[r]);
            srun[r] += e;
            attn[((size_t)b * 1024 + mb + 4 * lg + r) * 1024 + cf * 16 + lr] = f2bf(e);
        }
    }
#pragma unroll
    for (int r = 0; r < 4; r++) {
#pragma unroll
        for (int m = 1; m < 16; m <<= 1) srun[r] += __shfl_xor(srun[r], m);
    }
    if (lr == 0) {
#pragma unroll
        for (int r = 0; r < 4; r++) sr[b * 1024 + mb + 4 * lg + r] = 1.0f / srun[r];
    }
}

// ---------------- value GEMMs: 256x256 block tile, 8 waves of 64x128 ----------------
__global__ __launch_bounds__(512, 2) void k_value(const u16* __restrict__ attnA, const u16* __restrict__ attnB,
                                                  const u16* __restrict__ pv, const u16* __restrict__ ad,
                                                  const u16* __restrict__ xT, const float* __restrict__ tmA,
                                                  const float* __restrict__ srA, const float* __restrict__ srB,
                                                  const float* __restrict__ alpha, const float* __restrict__ beta,
                                                  u16* __restrict__ catT) {
    extern __shared__ __align__(16) char dyn[];
    const int id = blockIdx.x;
    const int xcd = id & 7, j = id >> 3;
    const int z = xcd + 8 * (j & 3);
    const int tile = j >> 2;
    const int mbt = tile & 3, cbt = tile >> 2;
    const int b = z & 15, var = z >> 4;
    const u16* Aorig = (var ? attnB : attnA) + ((size_t)b * 1024 + mbt * 256) * 1024;
    const u16* Borig = (var ? ad : pv) + ((size_t)b * 512 + cbt * 256) * 1024;
    const float* sr = (var ? srB : srA) + b * 1024;

    const int tid = threadIdx.x;
    const int l = tid & 63, w = tid >> 6;
    const int lr = l & 15, lg = l >> 4;
    const int ow = w >> 1, pw = w & 1;

    auto stageT = [&](int t, int s) {
        char* base = dyn + s * 32768;
#pragma unroll
        for (int it = 0; it < 2; it++) {
            int idx = it * 512 + tid;
            int row = idx & 255, g = idx >> 8;
            gload16(Aorig + (size_t)row * 1024 + t * 32 + g * 8, base + g * 4096 + row * 16);
        }
#pragma unroll
        for (int it = 0; it < 2; it++) {
            int idx = it * 512 + tid;
            int row = idx & 255, g = idx >> 8;
            gload16(Borig + (size_t)row * 1024 + t * 32 + g * 8, base + 16384 + g * 4096 + row * 16);
        }
    };

    f32x4 acc[4][8];
#pragma unroll
    for (int i = 0; i < 4; i++)
#pragma unroll
        for (int jj = 0; jj < 8; jj++) acc[i][jj] = f32x4{0.f, 0.f, 0.f, 0.f};

    stageT(0, 0);
    stageT(1, 1);
#pragma unroll 1
    for (int q = 0; q < 32; q++) {
        int qq = q + 2; if (qq >= 32) qq -= 32;
        stageT(qq, (q + 2) % 3);
        asm volatile("s_waitcnt vmcnt(8)" ::: "memory");
        __builtin_amdgcn_s_barrier();
        const char* A = dyn + (q % 3) * 32768;
        const char* B = A + 16384;
        bf16x8 af[4], bb[8];
#pragma unroll
        for (int i = 0; i < 4; i++) af[i] = *(const bf16x8*)(A + lg * 4096 + (ow * 64 + 16 * i + lr) * 16);
#pragma unroll
        for (int i = 0; i < 8; i++) bb[i] = *(const bf16x8*)(B + lg * 4096 + (pw * 128 + 16 * i + lr) * 16);
        __builtin_amdgcn_s_setprio(1);
#pragma unroll
        for (int ri = 0; ri < 4; ri++)
#pragma unroll
            for (int ci = 0; ci < 8; ci++) acc[ri][ci] = MFMA(af[ri], bb[ci], acc[ri][ci]);
        __builtin_amdgcn_s_setprio(0);
        __builtin_amdgcn_s_barrier();
    }
    asm volatile("s_waitcnt vmcnt(0)" ::: "memory");

    float sc = var ? alpha[0] : beta[0];
#pragma unroll
    for (int ri = 0; ri < 4; ri++) {
#pragma unroll
        for (int r = 0; r < 4; r++) {
            int m = mbt * 256 + ow * 64 + 16 * ri + 4 * lg + r;
            int pidx = ((m >> 5) + 1) * 34 + (m & 31) + 1;
            float ivm = sr[m];
#pragma unroll
            for (int ci = 0; ci < 8; ci++) {
                int c = cbt * 256 + pw * 128 + 16 * ci + lr;
                float av = acc[ri][ci][r] * ivm;
                float res;
                if (var == 0) {
                    float xv = bf2f(xT[((size_t)b * 1024 + m) * 512 + c]);
                    res = (1.f - sc) * xv + sc * av;
                } else {
                    float tm = tmA[b * 512 + c];
                    float adv = bf2f(ad[((size_t)b * 512 + c) * 1024 + m]);
                    res = (1.f - sc) * (1024.f * tm - av) + sc * adv;
                }
                catT[((size_t)b * NPADR + pidx) * 1024 + (var ? 512 : 0) + c] = f2bf(res);
            }
        }
    }
}

// ---------------- 3x3 conv: K=64 phases, 9 A-slots; buf1 B-stage hoisted to u=1 ----------------
// 512 thr, block 128o x 256p, grid 256, XCD swizzle.
// LDS 122880B: A 9 slots x 8KB @0 (slot = tap_step % 9); B 2 x 24KB @73728.
// stageB(buf1) at u=1 (3-phase-early; safe: laggards at u=0 read buf0 only);
// stageB(buf0') stays u=6 (earliest safe: u=4 compute reads buf0).
// vmcnt per u (FIFO re-derived): {4,7,7,7,6,4,7,7,7}.
__global__ __launch_bounds__(512, 1) void k_conv(const u16* __restrict__ wt, const u16* __restrict__ catT,
                                                 const float* __restrict__ bc, float* __restrict__ out) {
    extern __shared__ __align__(16) char dyn[];
    const int id = blockIdx.x;
    const int xcd = id & 7, j = id >> 3;
    const int obt = j & 3;
    const int pbb = xcd + 8 * (j >> 2);
    const int pbt = pbb & 3, b = pbb >> 2;

    const int tid = threadIdx.x;
    const int l = tid & 63, w = tid >> 6;      // 8 waves
    const int lr = l & 15, lg = l >> 4;
    const int ob = obt * 128;
    const int pb = pbt * 256;
    const int r0 = pbt * 8;
    const int ow = w >> 2, pw = w & 3;
    const u16* catB = catT + (size_t)b * NPADR * 1024 + (size_t)r0 * 34 * 1024;

    auto stageA = [&](int tap, int ckoff, int slot) {
        char* base = dyn + slot * 8192;
        int row = tid & 127, g = tid >> 7;
        gload16(wt + ((size_t)tap * 512 + ob + row) * 1024 + ckoff + g * 8,
                base + g * 2048 + row * 16);
    };
    auto stageB = [&](int ckoff, int sel) {
        char* base = dyn + 73728 + sel * 24576;
#pragma unroll
        for (int it = 0; it < 3; it++) {
            int idx = it * 512 + tid;
            int g = idx / 384;
            int row = idx - g * 384;
            gload16(catB + (size_t)row * 1024 + ckoff + g * 8,
                    base + g * 6144 + row * 16);
        }
    };

    int aoff[4], rbase[4];
#pragma unroll
    for (int i = 0; i < 4; i++) {
        aoff[i] = lg * 2048 + (ow * 64 + 16 * i + lr) * 16;
        int p = pw * 64 + 16 * i + lr;
        rbase[i] = ((p >> 5) + 1) * 34 + (p & 31) + 1;
    }

    f32x4 acc[4][4];
#pragma unroll
    for (int i = 0; i < 4; i++)
#pragma unroll
        for (int jj = 0; jj < 4; jj++) acc[i][jj] = f32x4{0.f, 0.f, 0.f, 0.f};

    // prologue FIFO: A(step0), A(step1), B(ck0)x3, A(step2), A(step3) -> slots 0,1,2,3
    stageA(0, 0, 0);
    stageA(1, 0, 1);
    stageB(0, 0);
    stageA(2, 0, 2);
    stageA(3, 0, 3);

    // compile-time tables: staged tap-steps s0=2u+4, s1=2u+5 within the 18-step block
    static constexpr int TAPS0[9] = {4, 6, 8, 1, 3, 5, 7, 0, 2};   // (2u+4) % 9
    static constexpr int CKD0[9]  = {0, 0, 0, 1, 1, 1, 1, 2, 2};   // (2u+4) / 9
    static constexpr int TAPS1[9] = {5, 7, 0, 2, 4, 6, 8, 1, 3};   // (2u+5) % 9
    static constexpr int CKD1[9]  = {0, 0, 1, 1, 1, 1, 1, 2, 2};   // (2u+5) / 9
    static constexpr int DROW0[9] = {-35, -33, 0, 33, 35, -34, -1, 1, 34};   // drow(tap(2u))
    static constexpr int DROW1[9] = {-34, -1, 1, 34, -35, -33, 0, 33, 35};   // drow(tap(2u+1))
    static constexpr int SLC0[9] = {0, 2, 4, 6, 8, 1, 3, 5, 7};    // (2u) % 9
    static constexpr int SLC1[9] = {1, 3, 5, 7, 0, 2, 4, 6, 8};    // (2u+1) % 9
    static constexpr int SLS0[9] = {4, 6, 8, 1, 3, 5, 7, 0, 2};    // (2u+4) % 9
    static constexpr int SLS1[9] = {5, 7, 0, 2, 4, 6, 8, 1, 3};    // (2u+5) % 9
    static constexpr int VMC[9]  = {4, 7, 7, 7, 6, 4, 7, 7, 7};    // counted vmcnt per u

#pragma unroll 1
    for (int cc = 0; cc < 16; cc++) {
#pragma unroll
        for (int u = 0; u < 9; u++) {
            {
                int ck = 2 * cc + CKD0[u];
                stageA(TAPS0[u], (ck >= 32 ? 0 : ck) * 32, SLS0[u]);
            }
            {
                int ck = 2 * cc + CKD1[u];
                stageA(TAPS1[u], (ck >= 32 ? 0 : ck) * 32, SLS1[u]);
            }
            if (u == 1) { int cn = 2 * cc + 1; stageB(cn * 32, 1); }
            if (u == 6) { int cn = 2 * cc + 2; stageB((cn >= 32 ? 0 : cn) * 32, 0); }
            if (VMC[u] == 4)      asm volatile("s_waitcnt vmcnt(4)" ::: "memory");
            else if (VMC[u] == 6) asm volatile("s_waitcnt vmcnt(6)" ::: "memory");
            else                  asm volatile("s_waitcnt vmcnt(7)" ::: "memory");
            __builtin_amdgcn_s_barrier();
            const char* A0 = dyn + SLC0[u] * 8192;
            const char* A1 = dyn + SLC1[u] * 8192;
            const char* B0 = dyn + 73728 + ((u >= 5) ? 24576 : 0);
            const char* B1 = dyn + 73728 + ((u >= 4) ? 24576 : 0);
            bf16x8 af0[4], bb0[4], af1[4], bb1[4];
#pragma unroll
            for (int i = 0; i < 4; i++) {
                af0[i] = *(const bf16x8*)(A0 + aoff[i]);
                bb0[i] = *(const bf16x8*)(B0 + lg * 6144 + (rbase[i] + DROW0[u]) * 16);
            }
#pragma unroll
            for (int i = 0; i < 4; i++) {
                af1[i] = *(const bf16x8*)(A1 + aoff[i]);
                bb1[i] = *(const bf16x8*)(B1 + lg * 6144 + (rbase[i] + DROW1[u]) * 16);
            }
            __builtin_amdgcn_s_setprio(1);
#pragma unroll
            for (int ri = 0; ri < 4; ri++)
#pragma unroll
                for (int ci = 0; ci < 4; ci++) acc[ri][ci] = MFMA(af0[ri], bb0[ci], acc[ri][ci]);
#pragma unroll
            for (int ri = 0; ri < 4; ri++)
#pragma unroll
                for (int ci = 0; ci < 4; ci++) acc[ri][ci] = MFMA(af1[ri], bb1[ci], acc[ri][ci]);
            __builtin_amdgcn_s_setprio(0);
        }
    }
    asm volatile("s_waitcnt vmcnt(0)" ::: "memory");
#pragma unroll
    for (int ri = 0; ri < 4; ri++) {
#pragma unroll
        for (int r = 0; r < 4; r++) {
            int o = ob + 16 * ri + 4 * lg + r;
            float bias = bc[o];
#pragma unroll
            for (int ci = 0; ci < 4; ci++) {
                int p = pb + pw * 64 + 16 * ci + lr;
                float v = acc[ri][ci][r] + bias;
                v = (v >= 0.f) ? v : 0.2f * v;
                (void)ow;
                out[((size_t)b * 512 + (o + ow * 64)) * 1024 + p] = v;
            }
        }
    }
}

// ---------------- launch ----------------
extern "C" void kernel_launch(void* const* d_in, const int* in_sizes, int n_in,
                              void* d_out, int out_size, void* d_ws, size_t ws_size,
                              hipStream_t stream) {
    (void)in_sizes; (void)n_in; (void)out_size; (void)ws_size;
    const float* inp = (const float*)d_in[0];
    const float* x   = (const float*)d_in[1];
    const float* y   = (const float*)d_in[2];
    const float* Wq  = (const float*)d_in[3];
    const float* bq  = (const float*)d_in[4];
    const float* Wk  = (const float*)d_in[5];
    const float* bk  = (const float*)d_in[6];
    const float* Wv  = (const float*)d_in[7];
    const float* bv  = (const float*)d_in[8];
    const float* Wc  = (const float*)d_in[9];
    const float* bc  = (const float*)d_in[10];
    const float* alpha = (const float*)d_in[11];
    const float* beta  = (const float*)d_in[12];
    float* out = (float*)d_out;

    char* ws = (char*)d_ws;
    u16* xT   = (u16*)(ws + OFF_XT);
    u16* yT   = (u16*)(ws + OFF_YT);
    u16* pjx  = (u16*)(ws + OFF_PJX);
    u16* pjy  = (u16*)(ws + OFF_PJY);
    u16* pv   = (u16*)(ws + OFF_PV);
    u16* ad   = (u16*)(ws + OFF_AD);
    u16* attnA = (u16*)(ws + OFF_ATTN);
    u16* attnB = (u16*)(ws + OFF_ATT2);
    u16* catT = (u16*)(ws + OFF_CATT);
    u16* wqk  = (u16*)(ws + OFF_WQK);
    u16* wv   = (u16*)(ws + OFF_WV);
    u16* wt   = (u16*)(ws + OFF_WT);
    float* srA = (float*)(ws + OFF_SA);
    float* tmA = (float*)(ws + OFF_TM);
    float* srB = (float*)(ws + OFF_SB);

    hipFuncSetAttribute((const void*)k_conv,  hipFuncAttributeMaxDynamicSharedMemorySize, 122880);
    hipFuncSetAttribute((const void*)k_value, hipFuncAttributeMaxDynamicSharedMemorySize, 98304);

    k_prep_w<<<1024, 256, 0, stream>>>(Wq, Wk, Wv, wqk, wv);
    k_prep_wt<<<2048, 256, 0, stream>>>(Wc, wt);
    k_border<<<dim3(132, 16), 256, 0, stream>>>(catT);
    k_stats<<<8192, 256, 0, stream>>>(x, inp, ad, tmA);
    k_transpose<<<dim3(128, 16, 2), 256, 0, stream>>>(x, y, xT, yT);
    k_proj<<<dim3(8, 16, 2), 256, 0, stream>>>(xT, yT, wqk, bq, bk, pjx, pjy);
    k_pv<<<dim3(8, 4, 16), 256, 0, stream>>>(xT, wv, bv, pv);
    k_score<<<dim3(256, 2), 256, 0, stream>>>(pjx, pjy, attnA, attnB, srA, srB);
    k_value<<<256, 512, 98304, stream>>>(attnA, attnB, pv, ad, xT, tmA, srA, srB, alpha, beta, catT);
    k_conv<<<256, 512, 122880, stream>>>(wt, catT, bc, out);
}